// Round 5
// baseline (2470.295 us; speedup 1.0000x reference)
//
#include <hip/hip_runtime.h>
#include <hip/hip_bf16.h>
#include <math.h>

// ---------------- problem constants ----------------
#define BB 32
#define NN 512
#define BN 16384          // BB*NN
#define DD 1024
#define HID 512
#define G4 2048           // 4*HID
#define HLEN 15
#define IND 4
#define EPS 1e-5f

typedef __bf16 v8bf __attribute__((ext_vector_type(8)));
typedef float  v4f  __attribute__((ext_vector_type(4)));

__device__ __forceinline__ void async_copy16(const __bf16* gsrc, __bf16* ldst) {
    __builtin_amdgcn_global_load_lds(
        (const __attribute__((address_space(1))) void*)gsrc,
        (__attribute__((address_space(3))) void*)ldst, 16, 0, 0);
}

#define VMCNT4 asm volatile("s_waitcnt vmcnt(4)" ::: "memory")
#define VMCNT0 asm volatile("s_waitcnt vmcnt(0)" ::: "memory")
#define LGKM0  asm volatile("s_waitcnt lgkmcnt(0)" ::: "memory")
#define MEMFENCE asm volatile("" ::: "memory")

// fast transcendentals: v_exp_f32 + v_rcp_f32 (rel err ~1e-6, fine vs 0.11 threshold)
#define LOG2E 1.44269504f
__device__ __forceinline__ float sigmf(float x) {
    return __builtin_amdgcn_rcpf(1.0f + __builtin_amdgcn_exp2f(-LOG2E * x));
}
__device__ __forceinline__ float tanh_fast(float x) {
    return 1.0f - 2.0f * __builtin_amdgcn_rcpf(1.0f + __builtin_amdgcn_exp2f(2.0f * LOG2E * x));
}

// ---------------- weight prep ----------------
__global__ void convert_w(const float* __restrict__ Whh, const float* __restrict__ Wrel,
                          const float* __restrict__ Wih, const float* __restrict__ bih,
                          const float* __restrict__ bhh,
                          __bf16* __restrict__ whh_b, __bf16* __restrict__ wrel_b,
                          float* __restrict__ wih_i, float* __restrict__ bsum) {
    int i = blockIdx.x * 256 + threadIdx.x;
    if (i < G4 * HID) whh_b[i] = (__bf16)Whh[i];
    if (i < DD * HID) wrel_b[i] = (__bf16)Wrel[i];
    if (i < G4) {
        int uu = i >> 2, gi = i & 3;
        int src = gi * HID + uu;
        wih_i[i * 4 + 0] = Wih[src * 4 + 0];
        wih_i[i * 4 + 1] = Wih[src * 4 + 1];
        wih_i[i * 4 + 2] = Wih[src * 4 + 2];
        wih_i[i * 4 + 3] = Wih[src * 4 + 3];
        bsum[i] = bih[src] + bhh[src];
    }
}

// ---------------- per-batch gate alpha ----------------
__global__ void alpha_kernel(const float* __restrict__ es, const float* __restrict__ gc,
                             const float* __restrict__ W_g1, const float* __restrict__ b_g1,
                             const float* __restrict__ W_g2, const float* __restrict__ b_g2,
                             float* __restrict__ alpha) {
    int b = threadIdx.x;
    if (b >= BB) return;
    float c0 = es[b], c1 = gc[b];
    float acc = b_g2[0];
    for (int k = 0; k < 16; ++k) {
        float hk = c0 * W_g1[k * 2] + c1 * W_g1[k * 2 + 1] + b_g1[k];
        hk = fmaxf(hk, 0.0f);
        acc += hk * W_g2[k];
    }
    alpha[b] = 1.0f / (1.0f + expf(-acc));
}

// ---------------- persistent LSTM: helpers ----------------
__device__ __forceinline__ void stage4(const __bf16* pA, const __bf16* pB,
                                       __bf16* dA, __bf16* dB) {
    async_copy16(pA,              dA);
    async_copy16(pA + 64 * HID,   dA + 2048);
    async_copy16(pB,              dB);
    async_copy16(pB + 1024 * HID, dB + 2048);   // gates 2,3 copy
}

// 3-buffer prefetch-distance-2 pipeline, one barrier per k-iter (round-4 proven).
// LGKM0 before each barrier guarantees this wave's prior ds_reads completed before
// any wave restages that buffer (closes the compiler-reorder race, rule #18).
__device__ __forceinline__ void gemm_tile_lstm(const __bf16* __restrict__ gA,
                                               const __bf16* __restrict__ gB,
                                               __bf16* lA, __bf16* lB,
                                               const __bf16* sAb, const __bf16* sBb,
                                               int wm, int wn16, int mrow, int pc,
                                               v4f (&acc)[4][4]) {
    stage4(gA,      gB,      lA,        lB);
    stage4(gA + 32, gB + 32, lA + 4096, lB + 4096);
    #pragma unroll
    for (int k = 0; k < 16; ++k) {
        LGKM0;
        if (k < 15) { VMCNT4; } else { VMCNT0; }
        __builtin_amdgcn_s_barrier();
        MEMFENCE;
        if (k + 2 < 16)
            stage4(gA + (k + 2) * 32, gB + (k + 2) * 32,
                   lA + ((k + 2) % 3) * 4096, lB + ((k + 2) % 3) * 4096);
        const __bf16* bA = sAb + (k % 3) * 4096;
        const __bf16* bB = sBb + (k % 3) * 4096;
        v8bf af[4], bfr[4];
        #pragma unroll
        for (int i = 0; i < 4; ++i) af[i]  = *(const v8bf*)(bA + (wm + i * 16 + mrow) * 32 + pc);
        #pragma unroll
        for (int j = 0; j < 4; ++j) bfr[j] = *(const v8bf*)(bB + (j * 32 + wn16 + mrow) * 32 + pc);
        #pragma unroll
        for (int i = 0; i < 4; ++i)
            #pragma unroll
            for (int j = 0; j < 4; ++j)
                acc[i][j] = __builtin_amdgcn_mfma_f32_16x16x32_bf16(af[i], bfr[j], acc[i][j], 0, 0, 0);
    }
    __syncthreads();   // all waves done reading before caller restages buffers 0/1
}

__device__ __forceinline__ void cell_init(float (&cS)[4][4], int bm, int wm, int crow4,
                                          int u_glob, const float* __restrict__ traj,
                                          const float (&wv)[4][4], const float (&bs4)[4],
                                          __bf16* __restrict__ hout) {
    #pragma unroll
    for (int i = 0; i < 4; ++i) {
        const int growb = bm * 128 + wm + i * 16 + crow4;
        #pragma unroll
        for (int r = 0; r < 4; ++r) {
            const int grow = growb + r;
            const float4 x = *(const float4*)(traj + (size_t)grow * (HLEN * IND));
            float g[4];
            #pragma unroll
            for (int gi = 0; gi < 4; ++gi)
                g[gi] = bs4[gi] + wv[gi][0] * x.x + wv[gi][1] * x.y + wv[gi][2] * x.z + wv[gi][3] * x.w;
            float ig = sigmf(g[0]);
            float gg = tanh_fast(g[2]);
            float og = sigmf(g[3]);
            float cn = ig * gg;                 // f*c0 = 0
            cS[i][r] = cn;
            hout[(size_t)grow * HID + u_glob] = (__bf16)(og * tanh_fast(cn));
        }
    }
}

__device__ __forceinline__ void cell_epi(const v4f (&acc)[4][4], float (&cS)[4][4],
                                         int bm, int t, int wm, int crow4, int u_glob,
                                         const float* __restrict__ traj,
                                         const float (&wv)[4][4], const float (&bs4)[4],
                                         __bf16* __restrict__ hout) {
    #pragma unroll
    for (int i = 0; i < 4; ++i) {
        const int growb = bm * 128 + wm + i * 16 + crow4;
        #pragma unroll
        for (int r = 0; r < 4; ++r) {
            const int grow = growb + r;
            const float4 x = *(const float4*)(traj + (size_t)grow * (HLEN * IND) + t * IND);
            float g[4];
            #pragma unroll
            for (int gi = 0; gi < 4; ++gi)
                g[gi] = acc[i][gi][r] + bs4[gi]
                      + wv[gi][0] * x.x + wv[gi][1] * x.y + wv[gi][2] * x.z + wv[gi][3] * x.w;
            float ig = sigmf(g[0]);
            float fg = sigmf(g[1]);
            float gg = tanh_fast(g[2]);
            float og = sigmf(g[3]);
            float cn = fg * cS[i][r] + ig * gg;
            cS[i][r] = cn;
            hout[(size_t)grow * HID + u_glob] = (__bf16)(og * tanh_fast(cn));
        }
    }
}

// sense/generation grid barrier; agent-scope acq/rel handles cross-XCD L2 coherence.
__device__ __forceinline__ void grid_sync(unsigned* bar) {
    __syncthreads();                       // drains vmcnt: all h stores in L2
    if (threadIdx.x == 0) {
        unsigned g = __hip_atomic_load(&bar[1], __ATOMIC_RELAXED, __HIP_MEMORY_SCOPE_AGENT);
        unsigned a = __hip_atomic_fetch_add(&bar[0], 1u, __ATOMIC_ACQ_REL, __HIP_MEMORY_SCOPE_AGENT);
        if (a == gridDim.x - 1) {
            __hip_atomic_store(&bar[0], 0u, __ATOMIC_RELAXED, __HIP_MEMORY_SCOPE_AGENT);
            __hip_atomic_store(&bar[1], g + 1u, __ATOMIC_RELEASE, __HIP_MEMORY_SCOPE_AGENT);
        } else {
            while (__hip_atomic_load(&bar[1], __ATOMIC_ACQUIRE, __HIP_MEMORY_SCOPE_AGENT) == g)
                __builtin_amdgcn_s_sleep(2);
        }
    }
    __syncthreads();
}

// ---------------- persistent fused LSTM (all 15 steps, c in registers) ----------------
// 512 blocks x 256 thr (2/CU co-resident). Block b: bn = b&15 (units [bn*32,+32)),
// bg = b>>4 (rows [bg*512,+512) as 4 sub-tiles of 128 rows). c state never leaves VGPRs.
__global__ __launch_bounds__(256, 2) void lstm_persist(const __bf16* __restrict__ whh,
                                                       const float* __restrict__ traj,
                                                       const float* __restrict__ wih_i,
                                                       const float* __restrict__ bsum,
                                                       __bf16* __restrict__ h0,
                                                       __bf16* __restrict__ h1,
                                                       unsigned* __restrict__ bar) {
    __shared__ __bf16 sA[3][128][32];   // 24 KB
    __shared__ __bf16 sB[3][128][32];   // 24 KB : rows = gate*32 + (u-u0)

    const int tid  = threadIdx.x;
    const int lane = tid & 63;
    const int wave = tid >> 6;
    const int wm   = (wave & 1) * 64;
    const int wn16 = (wave >> 1) * 16;
    const int b  = blockIdx.x;
    const int bn = b & 15;
    const int bg = b >> 4;
    const int u0 = bn * 32;

    const int mrow   = lane & 15;
    const int pc     = ((lane >> 4) ^ ((mrow >> 1) & 3)) * 8;
    const int crow4  = (lane >> 4) * 4;
    const int u_glob = u0 + wn16 + mrow;

    const int srow   = tid >> 2;
    const int schunk = (tid & 3) ^ ((srow >> 1) & 3);
    const __bf16* gB = whh + (size_t)((srow >> 5) * 512 + u0 + (srow & 31)) * HID + schunk * 8;
    __bf16* lA = &sA[0][0][0] + wave * 512;
    __bf16* lB = &sB[0][0][0] + wave * 512;

    float wv[4][4], bs4[4];
    #pragma unroll
    for (int gi = 0; gi < 4; ++gi) {
        float4 wp = *(const float4*)(wih_i + (size_t)(u_glob * 4 + gi) * 4);
        wv[gi][0] = wp.x; wv[gi][1] = wp.y; wv[gi][2] = wp.z; wv[gi][3] = wp.w;
        bs4[gi] = bsum[u_glob * 4 + gi];
    }

    float c0r[4][4], c1r[4][4], c2r[4][4], c3r[4][4];   // named -> static indexing

    // ---- t = 0 (h0 = c0 = 0) ----
    cell_init(c0r, bg * 4 + 0, wm, crow4, u_glob, traj, wv, bs4, h0);
    cell_init(c1r, bg * 4 + 1, wm, crow4, u_glob, traj, wv, bs4, h0);
    cell_init(c2r, bg * 4 + 2, wm, crow4, u_glob, traj, wv, bs4, h0);
    cell_init(c3r, bg * 4 + 3, wm, crow4, u_glob, traj, wv, bs4, h0);

    grid_sync(bar);

    for (int t = 1; t < HLEN; ++t) {
        const __bf16* hin  = (t & 1) ? h0 : h1;   // hbuf[(t+1)&1]
        __bf16*       hout = (t & 1) ? h1 : h0;   // hbuf[t&1]
        for (int s = 0; s < 4; ++s) {
            const int bm = bg * 4 + s;
            const __bf16* gA = hin + (size_t)(bm * 128 + srow) * HID + schunk * 8;
            v4f acc[4][4] = {};
            gemm_tile_lstm(gA, gB, lA, lB, &sA[0][0][0], &sB[0][0][0],
                           wm, wn16, mrow, pc, acc);
            if      (s == 0) cell_epi(acc, c0r, bm, t, wm, crow4, u_glob, traj, wv, bs4, hout);
            else if (s == 1) cell_epi(acc, c1r, bm, t, wm, crow4, u_glob, traj, wv, bs4, hout);
            else if (s == 2) cell_epi(acc, c2r, bm, t, wm, crow4, u_glob, traj, wv, bs4, hout);
            else             cell_epi(acc, c3r, bm, t, wm, crow4, u_glob, traj, wv, bs4, hout);
        }
        if (t < HLEN - 1) grid_sync(bar);   // last step: kernel boundary syncs
    }
}

// ---------------- projection GEMM: hrel(16384x1024 bf16) = h @ W_rel^T ----------------
__global__ __launch_bounds__(256) void gemm_proj(const __bf16* __restrict__ A,
                                                 const __bf16* __restrict__ Bm,
                                                 __bf16* __restrict__ Cout) {
    __shared__ __bf16 sA[3][128][32];
    __shared__ __bf16 sB[3][128][32];
    const int K = HID, Nn = DD;
    const int tid  = threadIdx.x;
    const int lane = tid & 63;
    const int wave = tid >> 6;
    const int wm = (wave & 1) * 64;
    const int wn = (wave >> 1) * 64;
    const int bm = blockIdx.x;
    const int bn = blockIdx.y;

    v4f acc[4][4] = {};

    const int srow   = tid >> 2;
    const int schunk = (tid & 3) ^ ((srow >> 1) & 3);

    const __bf16* gA = A  + (size_t)(bm * 128 + srow) * K + schunk * 8;
    const __bf16* gB = Bm + (size_t)(bn * 128 + srow) * K + schunk * 8;
    __bf16* lA = &sA[0][0][0] + wave * 512;
    __bf16* lB = &sB[0][0][0] + wave * 512;

    const int mrow = lane & 15;
    const int pc   = ((lane >> 4) ^ ((mrow >> 1) & 3)) * 8;

    #define STAGE(buf, kt)                                        \
        do {                                                      \
            const __bf16* pA_ = gA + (kt) * 32;                   \
            const __bf16* pB_ = gB + (kt) * 32;                   \
            __bf16* dA_ = lA + (buf) * 4096;                      \
            __bf16* dB_ = lB + (buf) * 4096;                      \
            async_copy16(pA_,          dA_);                      \
            async_copy16(pA_ + 64 * K, dA_ + 2048);               \
            async_copy16(pB_,          dB_);                      \
            async_copy16(pB_ + 64 * K, dB_ + 2048);               \
        } while (0)

    STAGE(0, 0);
    STAGE(1, 1);
    #pragma unroll
    for (int k = 0; k < 16; ++k) {
        LGKM0;
        if (k < 15) { VMCNT4; } else { VMCNT0; }
        __builtin_amdgcn_s_barrier();
        MEMFENCE;
        if (k + 2 < 16) STAGE((k + 2) % 3, k + 2);
        const int cur = k % 3;
        v8bf af[4], bfr[4];
        #pragma unroll
        for (int i = 0; i < 4; ++i) af[i]  = *(v8bf*)&sA[cur][wm + i * 16 + mrow][pc];
        #pragma unroll
        for (int j = 0; j < 4; ++j) bfr[j] = *(v8bf*)&sB[cur][wn + j * 16 + mrow][pc];
        #pragma unroll
        for (int i = 0; i < 4; ++i)
            #pragma unroll
            for (int j = 0; j < 4; ++j)
                acc[i][j] = __builtin_amdgcn_mfma_f32_16x16x32_bf16(af[i], bfr[j], acc[i][j], 0, 0, 0);
    }
    #undef STAGE

    const int ccol  = lane & 15;
    const int crow4 = (lane >> 4) * 4;
    #pragma unroll
    for (int i = 0; i < 4; ++i)
        #pragma unroll
        for (int j = 0; j < 4; ++j) {
            int gm = bm * 128 + wm + i * 16 + crow4;
            int gn = bn * 128 + wn + j * 16 + ccol;
            #pragma unroll
            for (int r = 0; r < 4; ++r)
                Cout[(size_t)(gm + r) * Nn + gn] = (__bf16)acc[i][j][r];
        }
}

// ---------------- fused gate-mix + residual + LayerNorm ----------------
__global__ __launch_bounds__(256) void fuse_ln(const float* __restrict__ tokens,
                                               const __bf16* __restrict__ hrel,
                                               const float* __restrict__ habs_in,
                                               const float* __restrict__ W_abs,
                                               const float* __restrict__ alpha,
                                               const float* __restrict__ gamma,
                                               const float* __restrict__ beta,
                                               float* __restrict__ out) {
    const int row = blockIdx.x;
    const int b   = row >> 9;
    const float al = alpha[b];
    const float a0 = habs_in[(size_t)row * 2];
    const float a1 = habs_in[(size_t)row * 2 + 1];
    const int tid  = threadIdx.x;
    const int lane = tid & 63;
    const int wave = tid >> 6;

    __shared__ float red[4];

    float x[4];
    float s = 0.0f;
    #pragma unroll
    for (int q = 0; q < 4; ++q) {
        int dcol = tid + q * 256;
        float habs = a0 * W_abs[dcol * 2] + a1 * W_abs[dcol * 2 + 1];
        float v = tokens[(size_t)row * DD + dcol]
                + al * (float)hrel[(size_t)row * DD + dcol]
                + (1.0f - al) * habs;
        x[q] = v;
        s += v;
    }
    #pragma unroll
    for (int off = 32; off > 0; off >>= 1) s += __shfl_down(s, off);
    if (lane == 0) red[wave] = s;
    __syncthreads();
    float mu = (red[0] + red[1] + red[2] + red[3]) * (1.0f / DD);

    float vs = 0.0f;
    #pragma unroll
    for (int q = 0; q < 4; ++q) {
        float d = x[q] - mu;
        vs += d * d;
    }
    #pragma unroll
    for (int off = 32; off > 0; off >>= 1) vs += __shfl_down(vs, off);
    __syncthreads();
    if (lane == 0) red[wave] = vs;
    __syncthreads();
    float var = (red[0] + red[1] + red[2] + red[3]) * (1.0f / DD);
    float rstd = rsqrtf(var + EPS);

    #pragma unroll
    for (int q = 0; q < 4; ++q) {
        int dcol = tid + q * 256;
        out[(size_t)row * DD + dcol] = (x[q] - mu) * rstd * gamma[dcol] + beta[dcol];
    }
}

// ---------------- host launch ----------------
extern "C" void kernel_launch(void* const* d_in, const int* in_sizes, int n_in,
                              void* d_out, int out_size, void* d_ws, size_t ws_size,
                              hipStream_t stream) {
    const float* tokens   = (const float*)d_in[0];
    const float* traj     = (const float*)d_in[1];
    const float* habs     = (const float*)d_in[2];
    const float* espeed   = (const float*)d_in[3];
    const float* gconf    = (const float*)d_in[4];
    const float* W_ih     = (const float*)d_in[5];
    const float* W_hh     = (const float*)d_in[6];
    const float* b_ih     = (const float*)d_in[7];
    const float* b_hh     = (const float*)d_in[8];
    const float* W_rel    = (const float*)d_in[9];
    const float* W_abs    = (const float*)d_in[10];
    const float* W_g1     = (const float*)d_in[11];
    const float* b_g1     = (const float*)d_in[12];
    const float* W_g2     = (const float*)d_in[13];
    const float* b_g2     = (const float*)d_in[14];
    const float* gamma    = (const float*)d_in[15];
    const float* beta     = (const float*)d_in[16];
    float* out = (float*)d_out;

    char* ws = (char*)d_ws;
    size_t off = 0;
    __bf16* whh_b  = (__bf16*)(ws + off); off += (size_t)G4 * HID * 2;     // 2 MB
    __bf16* wrel_b = (__bf16*)(ws + off); off += (size_t)DD * HID * 2;     // 1 MB
    float*  wih_i  = (float*)(ws + off);  off += (size_t)G4 * 4 * 4;       // 32 KB
    float*  bsum   = (float*)(ws + off);  off += (size_t)G4 * 4;           // 8 KB
    __bf16* h0     = (__bf16*)(ws + off); off += (size_t)BN * HID * 2;     // 16 MB
    __bf16* h1     = (__bf16*)(ws + off); off += (size_t)BN * HID * 2;     // 16 MB
    __bf16* hrel   = (__bf16*)(ws + off); off += (size_t)BN * DD * 2;      // 32 MB
    float*  alpha  = (float*)(ws + off);  off += 256;
    unsigned* bar  = (unsigned*)(ws + off); off += 256;

    hipMemsetAsync(bar, 0, 8, stream);
    convert_w<<<(G4 * HID + 255) / 256, 256, 0, stream>>>(W_hh, W_rel, W_ih, b_ih, b_hh,
                                                          whh_b, wrel_b, wih_i, bsum);
    alpha_kernel<<<1, 64, 0, stream>>>(espeed, gconf, W_g1, b_g1, W_g2, b_g2, alpha);

    {
        void* kargs[] = {(void*)&whh_b, (void*)&traj, (void*)&wih_i, (void*)&bsum,
                         (void*)&h0, (void*)&h1, (void*)&bar};
        hipLaunchCooperativeKernel((const void*)lstm_persist, dim3(512), dim3(256),
                                   kargs, 0, stream);
    }

    // final h after t=14 is in h0
    gemm_proj<<<dim3(BN / 128, DD / 128), 256, 0, stream>>>(h0, wrel_b, hrel);
    fuse_ln<<<BN, 256, 0, stream>>>(tokens, hrel, habs, W_abs, alpha, gamma, beta, out);
}

// Round 6
// 1057.303 us; speedup vs baseline: 2.3364x; 2.3364x over previous
//
#include <hip/hip_runtime.h>
#include <hip/hip_bf16.h>
#include <math.h>

// ---------------- problem constants ----------------
#define BB 32
#define NN 512
#define BN 16384          // BB*NN
#define DD 1024
#define HID 512
#define G4 2048           // 4*HID
#define HLEN 15
#define IND 4
#define EPS 1e-5f

typedef __bf16 v8bf __attribute__((ext_vector_type(8)));
typedef float  v4f  __attribute__((ext_vector_type(4)));

__device__ __forceinline__ void async_copy16(const __bf16* gsrc, __bf16* ldst) {
    __builtin_amdgcn_global_load_lds(
        (const __attribute__((address_space(1))) void*)gsrc,
        (__attribute__((address_space(3))) void*)ldst, 16, 0, 0);
}

#define VMCNTI(n) asm volatile("s_waitcnt vmcnt(" #n ")" ::: "memory")
#define VMCNT4 VMCNTI(4)
#define VMCNT0 VMCNTI(0)
#define LGKM0  asm volatile("s_waitcnt lgkmcnt(0)" ::: "memory")
#define MEMFENCE asm volatile("" ::: "memory")

// fast transcendentals: v_exp_f32 + v_rcp_f32 (rel err ~1e-6, fine vs 0.11 threshold)
#define LOG2E 1.44269504f
__device__ __forceinline__ float sigmf(float x) {
    return __builtin_amdgcn_rcpf(1.0f + __builtin_amdgcn_exp2f(-LOG2E * x));
}
__device__ __forceinline__ float tanh_fast(float x) {
    return 1.0f - 2.0f * __builtin_amdgcn_rcpf(1.0f + __builtin_amdgcn_exp2f(2.0f * LOG2E * x));
}

// ---------------- weight prep ----------------
// whh_b: NATIVE layout bf16 2048x512 (gate blocks i,f,g,o of 512 rows each);
// wrel_b: bf16 1024x512; wih_i: unit-interleaved fp32 2048x4; bsum: b_ih+b_hh interleaved.
__global__ void convert_w(const float* __restrict__ Whh, const float* __restrict__ Wrel,
                          const float* __restrict__ Wih, const float* __restrict__ bih,
                          const float* __restrict__ bhh,
                          __bf16* __restrict__ whh_b, __bf16* __restrict__ wrel_b,
                          float* __restrict__ wih_i, float* __restrict__ bsum) {
    int i = blockIdx.x * 256 + threadIdx.x;
    if (i < G4 * HID) whh_b[i] = (__bf16)Whh[i];
    if (i < DD * HID) wrel_b[i] = (__bf16)Wrel[i];
    if (i < G4) {
        int uu = i >> 2, gi = i & 3;
        int src = gi * HID + uu;
        wih_i[i * 4 + 0] = Wih[src * 4 + 0];
        wih_i[i * 4 + 1] = Wih[src * 4 + 1];
        wih_i[i * 4 + 2] = Wih[src * 4 + 2];
        wih_i[i * 4 + 3] = Wih[src * 4 + 3];
        bsum[i] = bih[src] + bhh[src];
    }
}

// ---------------- per-batch gate alpha ----------------
__global__ void alpha_kernel(const float* __restrict__ es, const float* __restrict__ gc,
                             const float* __restrict__ W_g1, const float* __restrict__ b_g1,
                             const float* __restrict__ W_g2, const float* __restrict__ b_g2,
                             float* __restrict__ alpha) {
    int b = threadIdx.x;
    if (b >= BB) return;
    float c0 = es[b], c1 = gc[b];
    float acc = b_g2[0];
    for (int k = 0; k < 16; ++k) {
        float hk = c0 * W_g1[k * 2] + c1 * W_g1[k * 2 + 1] + b_g1[k];
        hk = fmaxf(hk, 0.0f);
        acc += hk * W_g2[k];
    }
    alpha[b] = 1.0f / (1.0f + expf(-acc));
}

// ---------------- t=0 cell (h0 = c0 = 0 -> gates from input only) ----------------
__global__ __launch_bounds__(256) void lstm_cell0(const float* __restrict__ traj,
                                                  const float* __restrict__ wih_i,
                                                  const float* __restrict__ bsum,
                                                  float* __restrict__ c,
                                                  __bf16* __restrict__ h) {
    int idx = blockIdx.x * 256 + threadIdx.x;   // row*512 + u
    int row = idx >> 9;
    float4 x = *(const float4*)(traj + (size_t)row * (HLEN * IND));   // t = 0, 16B aligned
    int u = idx & 511;
    float g[4];
    #pragma unroll
    for (int gi = 0; gi < 4; ++gi) {
        int j = u * 4 + gi;
        float4 w = *(const float4*)(wih_i + (size_t)j * 4);
        g[gi] = bsum[j] + w.x * x.x + w.y * x.y + w.z * x.z + w.w * x.w;
    }
    float ig = sigmf(g[0]);
    float gg = tanh_fast(g[2]);
    float og = sigmf(g[3]);
    float cn = ig * gg;                    // f*c0 = 0
    c[idx] = cn;
    h[idx] = (__bf16)(og * tanh_fast(cn));
}

// ================= 256x256 8-phase fused GEMM + LSTM cell =================
// Tile: 256 rows x 256 gate-cols (= 64 units x 4 gates, gate-strip layout).
// 8 waves (2M x 4N): wave = 128 rows x 64 cols (16 units x 4 gates).
// LDS 128 KiB: 2 dbuf x [A 32KB (256x64) | B 32KB (256 rows = gate*64+u, x64)].
// Per K-tile (BK=64): 4 quadrant-phases (ig,gh): (0,0)(1,0)(1,1)(0,1); each phase:
//   {ds_read frags | stage one half-tile of kt+1} -> counted vmcnt -> barrier ->
//   lgkmcnt(0)+sched_barrier(0) -> setprio(1) 16 MFMA setprio(0) -> barrier.
// Stage slots per K-tile: q0: A-full (4 glds), q1: B-lo (2), q2: B-hi (2), q3: none.
// vmcnt(6) at q1 (drains prev Bhi), vmcnt(2) at q3 (drains next A+Blo). Never 0
// mid-loop; staging targets only buffer^1 so write/read regions never alias.
// Swizzle (128B rows): 16B-chunk ^= (row>>2)&3 within each 64B k-slice, applied on
// the pre-swizzled GLOBAL source (glds dest linear) and on the ds_read address.
// Read-side f = (mrow>>2)&3 is per-lane constant. Conflict-free (slot=8r+ch mod 32).

__device__ __forceinline__ void bar_acq() {   // phase barrier + read-completion fence
    __builtin_amdgcn_s_barrier();
    LGKM0;
    __builtin_amdgcn_sched_barrier(0);        // rule 18: pin MFMA after lgkmcnt
}
__device__ __forceinline__ void bar_rel() {
    __builtin_amdgcn_s_barrier();
    MEMFENCE;
}

template<int IG, int GH, bool RA, bool RB>
__device__ __forceinline__ void phase_read(const __bf16* smb, int wave_m, int wn,
                                           int mrow, int pcs,
                                           v8bf (&ar)[4][2], v8bf (&br)[2][2][2]) {
    if (RA) {
        #pragma unroll
        for (int ii = 0; ii < 4; ++ii)
            #pragma unroll
            for (int ks = 0; ks < 2; ++ks)
                ar[ii][ks] = *(const v8bf*)(smb +
                    (wave_m * 128 + IG * 64 + ii * 16 + mrow) * 64 + ks * 32 + pcs);
    }
    if (RB) {
        #pragma unroll
        for (int g2 = 0; g2 < 2; ++g2)
            #pragma unroll
            for (int ks = 0; ks < 2; ++ks)
                br[GH][g2][ks] = *(const v8bf*)(smb + 16384 +
                    ((GH * 2 + g2) * 64 + wn * 16 + mrow) * 64 + ks * 32 + pcs);
    }
}

template<int IG, int GH>
__device__ __forceinline__ void phase_mfma(v8bf (&ar)[4][2], v8bf (&br)[2][2][2],
                                           v4f (&acc)[8][4]) {
    __builtin_amdgcn_s_setprio(1);
    #pragma unroll
    for (int ii = 0; ii < 4; ++ii)
        #pragma unroll
        for (int g2 = 0; g2 < 2; ++g2)
            #pragma unroll
            for (int ks = 0; ks < 2; ++ks)
                acc[IG * 4 + ii][GH * 2 + g2] = __builtin_amdgcn_mfma_f32_16x16x32_bf16(
                    ar[ii][ks], br[GH][g2][ks], acc[IG * 4 + ii][GH * 2 + g2], 0, 0, 0);
    __builtin_amdgcn_s_setprio(0);
}

__global__ __launch_bounds__(512, 2) void gemm_lstm(const __bf16* __restrict__ A,
                                                    const __bf16* __restrict__ Bm,
                                                    const float* __restrict__ traj,
                                                    const float* __restrict__ wih_i,
                                                    const float* __restrict__ bsum,
                                                    float* __restrict__ c,
                                                    __bf16* __restrict__ h_out,
                                                    int t) {
    __shared__ __bf16 sm[2][32768];   // 128 KiB: [buf][A 16384 elems | B 16384 elems]

    const int tid    = threadIdx.x;
    const int lane   = tid & 63;
    const int wave   = tid >> 6;      // 0..7
    const int wave_m = wave & 1;      // row half of 256
    const int wn     = wave >> 1;     // 0..3: unit sub-block of 16
    const int bm     = blockIdx.x;    // rows [bm*256, +256)
    const int ub     = blockIdx.y;    // units [ub*64, +64)

    const int mrow = lane & 15;
    const int pcs  = (((lane >> 4) ^ ((mrow >> 2) & 3)) << 3);   // swizzled read chunk (elems)

    // per-thread pre-swizzled global staging sources (kt=0); advance by kt*64 elems
    const __bf16* pa[4];
    const __bf16* pb[4];
    #pragma unroll
    for (int s = 0; s < 4; ++s) {
        const int ca = tid + s * 512;                  // chunk 0..2047
        const int r  = ca >> 3, p = ca & 7;
        const int sl = p >> 2, l2 = (p & 3) ^ ((r >> 2) & 3);
        pa[s] = A + (size_t)(bm * 256 + r) * HID + sl * 32 + l2 * 8;
        const int g = r >> 6, ul = r & 63;
        pb[s] = Bm + (size_t)(g * HID + ub * 64 + ul) * HID + sl * 32 + l2 * 8;
    }
    const int wb = wave * 512;        // wave-uniform LDS chunk base (elems)

    #define STAGE_A(buf, kt) do {                                        \
        async_copy16(pa[0] + (kt) * 64, &sm[buf][wb]);                   \
        async_copy16(pa[1] + (kt) * 64, &sm[buf][wb + 4096]);            \
        async_copy16(pa[2] + (kt) * 64, &sm[buf][wb + 8192]);            \
        async_copy16(pa[3] + (kt) * 64, &sm[buf][wb + 12288]); } while (0)
    #define STAGE_BLO(buf, kt) do {                                      \
        async_copy16(pb[0] + (kt) * 64, &sm[buf][16384 + wb]);           \
        async_copy16(pb[1] + (kt) * 64, &sm[buf][16384 + wb + 4096]); } while (0)
    #define STAGE_BHI(buf, kt) do {                                      \
        async_copy16(pb[2] + (kt) * 64, &sm[buf][16384 + wb + 8192]);    \
        async_copy16(pb[3] + (kt) * 64, &sm[buf][16384 + wb + 12288]); } while (0)

    v4f  acc[8][4] = {};
    v8bf ar[4][2];
    v8bf br[2][2][2];

    // prologue: K-tile 0 fully staged; Bhi may stay in flight until q1's vmcnt(6)
    STAGE_A(0, 0); STAGE_BLO(0, 0); STAGE_BHI(0, 0);
    VMCNTI(2);
    __builtin_amdgcn_s_barrier();
    MEMFENCE;

    #pragma unroll
    for (int kt = 0; kt < 7; ++kt) {
        const int cb = kt & 1, nb = cb ^ 1;
        const __bf16* smb = &sm[cb][0];
        // q0: (ig0, Blo)
        phase_read<0, 0, true, true>(smb, wave_m, wn, mrow, pcs, ar, br);
        if (nb) { STAGE_A(1, kt + 1); } else { STAGE_A(0, kt + 1); }
        bar_acq();  phase_mfma<0, 0>(ar, br, acc);  bar_rel();
        // q1: (ig1, Blo)
        phase_read<1, 0, true, false>(smb, wave_m, wn, mrow, pcs, ar, br);
        if (nb) { STAGE_BLO(1, kt + 1); } else { STAGE_BLO(0, kt + 1); }
        VMCNTI(6);
        bar_acq();  phase_mfma<1, 0>(ar, br, acc);  bar_rel();
        // q2: (ig1, Bhi) — A frags reused from q1
        phase_read<1, 1, false, true>(smb, wave_m, wn, mrow, pcs, ar, br);
        if (nb) { STAGE_BHI(1, kt + 1); } else { STAGE_BHI(0, kt + 1); }
        bar_acq();  phase_mfma<1, 1>(ar, br, acc);  bar_rel();
        // q3: (ig0, Bhi)
        phase_read<0, 1, true, false>(smb, wave_m, wn, mrow, pcs, ar, br);
        VMCNTI(2);
        bar_acq();  phase_mfma<0, 1>(ar, br, acc);  bar_rel();
    }

    // tail K-tile 7 (buffer 1): everything landed; no stages, no barriers
    VMCNT0;
    __builtin_amdgcn_s_barrier();
    MEMFENCE;
    {
        const __bf16* smb = &sm[1][0];
        phase_read<0, 0, true, true >(smb, wave_m, wn, mrow, pcs, ar, br);
        LGKM0; __builtin_amdgcn_sched_barrier(0);  phase_mfma<0, 0>(ar, br, acc);
        phase_read<1, 0, true, false>(smb, wave_m, wn, mrow, pcs, ar, br);
        LGKM0; __builtin_amdgcn_sched_barrier(0);  phase_mfma<1, 0>(ar, br, acc);
        phase_read<1, 1, false, true>(smb, wave_m, wn, mrow, pcs, ar, br);
        LGKM0; __builtin_amdgcn_sched_barrier(0);  phase_mfma<1, 1>(ar, br, acc);
        phase_read<0, 1, true, false>(smb, wave_m, wn, mrow, pcs, ar, br);
        LGKM0; __builtin_amdgcn_sched_barrier(0);  phase_mfma<0, 1>(ar, br, acc);
    }
    #undef STAGE_A
    #undef STAGE_BLO
    #undef STAGE_BHI

    // ---- register-only cell update: lane owns unit u_glob; 8x4 cells ----
    const int u_glob = ub * 64 + wn * 16 + mrow;
    const int crow4  = (lane >> 4) * 4;
    float wv[4][4], bs4[4];
    #pragma unroll
    for (int gi = 0; gi < 4; ++gi) {
        float4 wp = *(const float4*)(wih_i + (size_t)(u_glob * 4 + gi) * 4);
        wv[gi][0] = wp.x; wv[gi][1] = wp.y; wv[gi][2] = wp.z; wv[gi][3] = wp.w;
        bs4[gi] = bsum[u_glob * 4 + gi];
    }
    #pragma unroll
    for (int i = 0; i < 8; ++i) {
        const int growb = bm * 256 + wave_m * 128 + (i >> 2) * 64 + (i & 3) * 16 + crow4;
        #pragma unroll
        for (int r = 0; r < 4; ++r) {
            const int grow = growb + r;
            const float4 x = *(const float4*)(traj + (size_t)grow * (HLEN * IND) + t * IND);
            float g[4];
            #pragma unroll
            for (int gi = 0; gi < 4; ++gi)
                g[gi] = acc[i][gi][r] + bs4[gi]
                      + wv[gi][0] * x.x + wv[gi][1] * x.y + wv[gi][2] * x.z + wv[gi][3] * x.w;
            float ig = sigmf(g[0]);
            float fg = sigmf(g[1]);
            float gg = tanh_fast(g[2]);
            float og = sigmf(g[3]);
            size_t ci = (size_t)grow * HID + u_glob;
            float cn = fg * c[ci] + ig * gg;
            c[ci] = cn;
            h_out[ci] = (__bf16)(og * tanh_fast(cn));
        }
    }
}

// ---------------- projection GEMM: hrel(16384x1024 bf16) = h @ W_rel^T ----------------
__global__ __launch_bounds__(256) void gemm_proj(const __bf16* __restrict__ A,
                                                 const __bf16* __restrict__ Bm,
                                                 __bf16* __restrict__ Cout) {
    __shared__ __bf16 sA[3][128][32];
    __shared__ __bf16 sB[3][128][32];
    const int K = HID, Nn = DD;
    const int tid  = threadIdx.x;
    const int lane = tid & 63;
    const int wave = tid >> 6;
    const int wm = (wave & 1) * 64;
    const int wn = (wave >> 1) * 64;
    const int bm = blockIdx.x;
    const int bn = blockIdx.y;

    v4f acc[4][4] = {};

    const int srow   = tid >> 2;
    const int schunk = (tid & 3) ^ ((srow >> 1) & 3);

    const __bf16* gA = A  + (size_t)(bm * 128 + srow) * K + schunk * 8;
    const __bf16* gB = Bm + (size_t)(bn * 128 + srow) * K + schunk * 8;
    __bf16* lA = &sA[0][0][0] + wave * 512;
    __bf16* lB = &sB[0][0][0] + wave * 512;

    const int mrow = lane & 15;
    const int pc   = ((lane >> 4) ^ ((mrow >> 1) & 3)) * 8;

    #define STAGE(buf, kt)                                        \
        do {                                                      \
            const __bf16* pA_ = gA + (kt) * 32;                   \
            const __bf16* pB_ = gB + (kt) * 32;                   \
            __bf16* dA_ = lA + (buf) * 4096;                      \
            __bf16* dB_ = lB + (buf) * 4096;                      \
            async_copy16(pA_,          dA_);                      \
            async_copy16(pA_ + 64 * K, dA_ + 2048);               \
            async_copy16(pB_,          dB_);                      \
            async_copy16(pB_ + 64 * K, dB_ + 2048);               \
        } while (0)

    STAGE(0, 0);
    STAGE(1, 1);
    #pragma unroll
    for (int k = 0; k < 16; ++k) {
        if (k < 15) { VMCNT4; } else { VMCNT0; }
        __builtin_amdgcn_s_barrier();
        MEMFENCE;
        if (k + 2 < 16) STAGE((k + 2) % 3, k + 2);
        const int cur = k % 3;
        v8bf af[4], bfr[4];
        #pragma unroll
        for (int i = 0; i < 4; ++i) af[i]  = *(v8bf*)&sA[cur][wm + i * 16 + mrow][pc];
        #pragma unroll
        for (int j = 0; j < 4; ++j) bfr[j] = *(v8bf*)&sB[cur][wn + j * 16 + mrow][pc];
        #pragma unroll
        for (int i = 0; i < 4; ++i)
            #pragma unroll
            for (int j = 0; j < 4; ++j)
                acc[i][j] = __builtin_amdgcn_mfma_f32_16x16x32_bf16(af[i], bfr[j], acc[i][j], 0, 0, 0);
    }
    #undef STAGE

    const int ccol  = lane & 15;
    const int crow4 = (lane >> 4) * 4;
    #pragma unroll
    for (int i = 0; i < 4; ++i)
        #pragma unroll
        for (int j = 0; j < 4; ++j) {
            int gm = bm * 128 + wm + i * 16 + crow4;
            int gn = bn * 128 + wn + j * 16 + ccol;
            #pragma unroll
            for (int r = 0; r < 4; ++r)
                Cout[(size_t)(gm + r) * Nn + gn] = (__bf16)acc[i][j][r];
        }
}

// ---------------- fused gate-mix + residual + LayerNorm ----------------
__global__ __launch_bounds__(256) void fuse_ln(const float* __restrict__ tokens,
                                               const __bf16* __restrict__ hrel,
                                               const float* __restrict__ habs_in,
                                               const float* __restrict__ W_abs,
                                               const float* __restrict__ alpha,
                                               const float* __restrict__ gamma,
                                               const float* __restrict__ beta,
                                               float* __restrict__ out) {
    const int row = blockIdx.x;
    const int b   = row >> 9;
    const float al = alpha[b];
    const float a0 = habs_in[(size_t)row * 2];
    const float a1 = habs_in[(size_t)row * 2 + 1];
    const int tid  = threadIdx.x;
    const int lane = tid & 63;
    const int wave = tid >> 6;

    __shared__ float red[4];

    float x[4];
    float s = 0.0f;
    #pragma unroll
    for (int q = 0; q < 4; ++q) {
        int dcol = tid + q * 256;
        float habs = a0 * W_abs[dcol * 2] + a1 * W_abs[dcol * 2 + 1];
        float v = tokens[(size_t)row * DD + dcol]
                + al * (float)hrel[(size_t)row * DD + dcol]
                + (1.0f - al) * habs;
        x[q] = v;
        s += v;
    }
    #pragma unroll
    for (int off = 32; off > 0; off >>= 1) s += __shfl_down(s, off);
    if (lane == 0) red[wave] = s;
    __syncthreads();
    float mu = (red[0] + red[1] + red[2] + red[3]) * (1.0f / DD);

    float vs = 0.0f;
    #pragma unroll
    for (int q = 0; q < 4; ++q) {
        float d = x[q] - mu;
        vs += d * d;
    }
    #pragma unroll
    for (int off = 32; off > 0; off >>= 1) vs += __shfl_down(vs, off);
    __syncthreads();
    if (lane == 0) red[wave] = vs;
    __syncthreads();
    float var = (red[0] + red[1] + red[2] + red[3]) * (1.0f / DD);
    float rstd = rsqrtf(var + EPS);

    #pragma unroll
    for (int q = 0; q < 4; ++q) {
        int dcol = tid + q * 256;
        out[(size_t)row * DD + dcol] = (x[q] - mu) * rstd * gamma[dcol] + beta[dcol];
    }
}

// ---------------- host launch ----------------
extern "C" void kernel_launch(void* const* d_in, const int* in_sizes, int n_in,
                              void* d_out, int out_size, void* d_ws, size_t ws_size,
                              hipStream_t stream) {
    const float* tokens   = (const float*)d_in[0];
    const float* traj     = (const float*)d_in[1];
    const float* habs     = (const float*)d_in[2];
    const float* espeed   = (const float*)d_in[3];
    const float* gconf    = (const float*)d_in[4];
    const float* W_ih     = (const float*)d_in[5];
    const float* W_hh     = (const float*)d_in[6];
    const float* b_ih     = (const float*)d_in[7];
    const float* b_hh     = (const float*)d_in[8];
    const float* W_rel    = (const float*)d_in[9];
    const float* W_abs    = (const float*)d_in[10];
    const float* W_g1     = (const float*)d_in[11];
    const float* b_g1     = (const float*)d_in[12];
    const float* W_g2     = (const float*)d_in[13];
    const float* b_g2     = (const float*)d_in[14];
    const float* gamma    = (const float*)d_in[15];
    const float* beta     = (const float*)d_in[16];
    float* out = (float*)d_out;

    char* ws = (char*)d_ws;
    size_t off = 0;
    __bf16* whh_b  = (__bf16*)(ws + off); off += (size_t)G4 * HID * 2;     // 2 MB
    __bf16* wrel_b = (__bf16*)(ws + off); off += (size_t)DD * HID * 2;     // 1 MB
    float*  wih_i  = (float*)(ws + off);  off += (size_t)G4 * 4 * 4;       // 32 KB
    float*  bsum   = (float*)(ws + off);  off += (size_t)G4 * 4;           // 8 KB
    __bf16* h0     = (__bf16*)(ws + off); off += (size_t)BN * HID * 2;     // 16 MB
    __bf16* h1     = (__bf16*)(ws + off); off += (size_t)BN * HID * 2;     // 16 MB
    float*  c      = (float*)(ws + off);  off += (size_t)BN * HID * 4;     // 32 MB
    __bf16* hrel   = (__bf16*)(ws + off); off += (size_t)BN * DD * 2;      // 32 MB
    float*  alpha  = (float*)(ws + off);  off += 256;

    convert_w<<<(G4 * HID + 255) / 256, 256, 0, stream>>>(W_hh, W_rel, W_ih, b_ih, b_hh,
                                                          whh_b, wrel_b, wih_i, bsum);
    alpha_kernel<<<1, 64, 0, stream>>>(espeed, gconf, W_g1, b_g1, W_g2, b_g2, alpha);
    lstm_cell0<<<(BN * HID) / 256, 256, 0, stream>>>(traj, wih_i, bsum, c, h0);

    __bf16* hbuf[2] = {h0, h1};
    for (int t = 1; t < HLEN; ++t) {
        const __bf16* hin = hbuf[(t + 1) & 1];
        __bf16* hout = hbuf[t & 1];
        gemm_lstm<<<dim3(BN / 256, HID / 64), 512, 0, stream>>>(hin, whh_b, traj, wih_i, bsum,
                                                                c, hout, t);
    }
    // final h after t=14 is in hbuf[14&1] = h0
    gemm_proj<<<dim3(BN / 128, DD / 128), 256, 0, stream>>>(h0, wrel_b, hrel);
    fuse_ln<<<BN, 256, 0, stream>>>(tokens, hrel, habs, W_abs, alpha, gamma, beta, out);
}

// Round 7
// 868.289 us; speedup vs baseline: 2.8450x; 1.2177x over previous
//
#include <hip/hip_runtime.h>
#include <hip/hip_bf16.h>
#include <math.h>

// ---------------- problem constants ----------------
#define BB 32
#define NN 512
#define BN 16384          // BB*NN
#define DD 1024
#define HID 512
#define G4 2048           // 4*HID
#define HLEN 15
#define IND 4
#define EPS 1e-5f

typedef __bf16 v8bf __attribute__((ext_vector_type(8)));
typedef float  v4f  __attribute__((ext_vector_type(4)));

__device__ __forceinline__ void async_copy16(const __bf16* gsrc, __bf16* ldst) {
    __builtin_amdgcn_global_load_lds(
        (const __attribute__((address_space(1))) void*)gsrc,
        (__attribute__((address_space(3))) void*)ldst, 16, 0, 0);
}

#define VMCNTI(n) asm volatile("s_waitcnt vmcnt(" #n ")" ::: "memory")
#define VMCNT0 VMCNTI(0)
#define LGKM0  asm volatile("s_waitcnt lgkmcnt(0)" ::: "memory")
#define MEMFENCE asm volatile("" ::: "memory")

// fast transcendentals: v_exp_f32 + v_rcp_f32 (rel err ~1e-6, fine vs 0.11 threshold)
#define LOG2E 1.44269504f
__device__ __forceinline__ float sigmf(float x) {
    return __builtin_amdgcn_rcpf(1.0f + __builtin_amdgcn_exp2f(-LOG2E * x));
}
__device__ __forceinline__ float tanh_fast(float x) {
    return 1.0f - 2.0f * __builtin_amdgcn_rcpf(1.0f + __builtin_amdgcn_exp2f(2.0f * LOG2E * x));
}

// ---------------- weight prep ----------------
// whh_b: NATIVE layout bf16 2048x512 (gate blocks i,f,g,o of 512 rows each);
// wrel_b: bf16 1024x512; wih_i: unit-interleaved fp32 2048x4; bsum: b_ih+b_hh interleaved.
__global__ void convert_w(const float* __restrict__ Whh, const float* __restrict__ Wrel,
                          const float* __restrict__ Wih, const float* __restrict__ bih,
                          const float* __restrict__ bhh,
                          __bf16* __restrict__ whh_b, __bf16* __restrict__ wrel_b,
                          float* __restrict__ wih_i, float* __restrict__ bsum) {
    int i = blockIdx.x * 256 + threadIdx.x;
    if (i < G4 * HID) whh_b[i] = (__bf16)Whh[i];
    if (i < DD * HID) wrel_b[i] = (__bf16)Wrel[i];
    if (i < G4) {
        int uu = i >> 2, gi = i & 3;
        int src = gi * HID + uu;
        wih_i[i * 4 + 0] = Wih[src * 4 + 0];
        wih_i[i * 4 + 1] = Wih[src * 4 + 1];
        wih_i[i * 4 + 2] = Wih[src * 4 + 2];
        wih_i[i * 4 + 3] = Wih[src * 4 + 3];
        bsum[i] = bih[src] + bhh[src];
    }
}

// ---------------- per-batch gate alpha ----------------
__global__ void alpha_kernel(const float* __restrict__ es, const float* __restrict__ gc,
                             const float* __restrict__ W_g1, const float* __restrict__ b_g1,
                             const float* __restrict__ W_g2, const float* __restrict__ b_g2,
                             float* __restrict__ alpha) {
    int b = threadIdx.x;
    if (b >= BB) return;
    float c0 = es[b], c1 = gc[b];
    float acc = b_g2[0];
    for (int k = 0; k < 16; ++k) {
        float hk = c0 * W_g1[k * 2] + c1 * W_g1[k * 2 + 1] + b_g1[k];
        hk = fmaxf(hk, 0.0f);
        acc += hk * W_g2[k];
    }
    alpha[b] = 1.0f / (1.0f + expf(-acc));
}

// ---------------- t=0 cell (h0 = c0 = 0 -> gates from input only) ----------------
__global__ __launch_bounds__(256) void lstm_cell0(const float* __restrict__ traj,
                                                  const float* __restrict__ wih_i,
                                                  const float* __restrict__ bsum,
                                                  float* __restrict__ c,
                                                  __bf16* __restrict__ h) {
    int idx = blockIdx.x * 256 + threadIdx.x;   // row*512 + u
    int row = idx >> 9;
    float4 x = *(const float4*)(traj + (size_t)row * (HLEN * IND));   // t = 0, 16B aligned
    int u = idx & 511;
    float g[4];
    #pragma unroll
    for (int gi = 0; gi < 4; ++gi) {
        int j = u * 4 + gi;
        float4 w = *(const float4*)(wih_i + (size_t)j * 4);
        g[gi] = bsum[j] + w.x * x.x + w.y * x.y + w.z * x.z + w.w * x.w;
    }
    float ig = sigmf(g[0]);
    float gg = tanh_fast(g[2]);
    float og = sigmf(g[3]);
    float cn = ig * gg;                    // f*c0 = 0
    c[idx] = cn;
    h[idx] = (__bf16)(og * tanh_fast(cn));
}

// ================= 256x256 8-phase GEMM core =================
// Tile: 256 rows x 256 cols. 8 waves (2M x 4N): wave = 128 rows x 64 cols.
// LDS 128 KiB: 2 dbuf x [A 32KB (256x64) | B 32KB (256x64)], BK=64.
// SWIZZLE (fixed, round-7): rows are 128B -> bank = (slot*4 + w) mod 32 with 8
// 16B-slots per row; row stride vanishes mod 32 banks. Full 3-bit XOR needed:
// physical slot P = L ^ (row&7), L = ks*4 + chunk. Read addr: (ks*32) ^ pcs,
// pcs = ((lane>>4) ^ (mrow&7))*8  ->  each contiguous 8-lane group covers all
// 8 slots = all 32 banks: conflict-free. Write side: glds dest LINEAR; global
// source slot l = (chunk&7) ^ (row&7) (both-sides-or-neither, m104/m231).
// Per K-tile: 4 quadrant-phases (ig,gh): (0,0)(1,0)(1,1)(0,1); each:
//   {ds_read frags | stage half-tile of kt+1} -> counted vmcnt (6/2, never 0
//   mid-loop) -> barrier -> lgkmcnt(0)+sched_barrier(0) -> setprio MFMA -> barrier.

__device__ __forceinline__ void bar_acq() {   // phase barrier + read-completion fence
    __builtin_amdgcn_s_barrier();
    LGKM0;
    __builtin_amdgcn_sched_barrier(0);        // rule 18: pin MFMA after lgkmcnt
}
__device__ __forceinline__ void bar_rel() {
    __builtin_amdgcn_s_barrier();
    MEMFENCE;
}

template<int IG, int GH, bool RA, bool RB>
__device__ __forceinline__ void phase_read(const __bf16* smb, int wave_m, int wn,
                                           int mrow, int pcs,
                                           v8bf (&ar)[4][2], v8bf (&br)[2][2][2]) {
    if (RA) {
        #pragma unroll
        for (int ii = 0; ii < 4; ++ii)
            #pragma unroll
            for (int ks = 0; ks < 2; ++ks)
                ar[ii][ks] = *(const v8bf*)(smb +
                    (wave_m * 128 + IG * 64 + ii * 16 + mrow) * 64 + ((ks * 32) ^ pcs));
    }
    if (RB) {
        #pragma unroll
        for (int g2 = 0; g2 < 2; ++g2)
            #pragma unroll
            for (int ks = 0; ks < 2; ++ks)
                br[GH][g2][ks] = *(const v8bf*)(smb + 16384 +
                    ((GH * 2 + g2) * 64 + wn * 16 + mrow) * 64 + ((ks * 32) ^ pcs));
    }
}

template<int IG, int GH>
__device__ __forceinline__ void phase_mfma(v8bf (&ar)[4][2], v8bf (&br)[2][2][2],
                                           v4f (&acc)[8][4]) {
    __builtin_amdgcn_s_setprio(1);
    #pragma unroll
    for (int ii = 0; ii < 4; ++ii)
        #pragma unroll
        for (int g2 = 0; g2 < 2; ++g2)
            #pragma unroll
            for (int ks = 0; ks < 2; ++ks)
                acc[IG * 4 + ii][GH * 2 + g2] = __builtin_amdgcn_mfma_f32_16x16x32_bf16(
                    ar[ii][ks], br[GH][g2][ks], acc[IG * 4 + ii][GH * 2 + g2], 0, 0, 0);
    __builtin_amdgcn_s_setprio(0);
}

#define STAGE_A(buf, kt) do {                                        \
    async_copy16(pa[0] + (kt) * 64, &sm[buf][wb]);                   \
    async_copy16(pa[1] + (kt) * 64, &sm[buf][wb + 4096]);            \
    async_copy16(pa[2] + (kt) * 64, &sm[buf][wb + 8192]);            \
    async_copy16(pa[3] + (kt) * 64, &sm[buf][wb + 12288]); } while (0)
#define STAGE_BLO(buf, kt) do {                                      \
    async_copy16(pb[0] + (kt) * 64, &sm[buf][16384 + wb]);           \
    async_copy16(pb[1] + (kt) * 64, &sm[buf][16384 + wb + 4096]); } while (0)
#define STAGE_BHI(buf, kt) do {                                      \
    async_copy16(pb[2] + (kt) * 64, &sm[buf][16384 + wb + 8192]);    \
    async_copy16(pb[3] + (kt) * 64, &sm[buf][16384 + wb + 12288]); } while (0)

#define GEMM256_BODY                                                               \
    v4f  acc[8][4] = {};                                                           \
    v8bf ar[4][2];                                                                 \
    v8bf br[2][2][2];                                                              \
    STAGE_A(0, 0); STAGE_BLO(0, 0); STAGE_BHI(0, 0);                               \
    VMCNTI(2);                                                                     \
    __builtin_amdgcn_s_barrier();                                                  \
    MEMFENCE;                                                                      \
    _Pragma("unroll")                                                              \
    for (int kt = 0; kt < 7; ++kt) {                                               \
        const int nb = (kt & 1) ^ 1;                                               \
        const __bf16* smb = &sm[kt & 1][0];                                        \
        phase_read<0, 0, true, true>(smb, wave_m, wn, mrow, pcs, ar, br);          \
        if (nb) { STAGE_A(1, kt + 1); } else { STAGE_A(0, kt + 1); }               \
        bar_acq();  phase_mfma<0, 0>(ar, br, acc);  bar_rel();                     \
        phase_read<1, 0, true, false>(smb, wave_m, wn, mrow, pcs, ar, br);         \
        if (nb) { STAGE_BLO(1, kt + 1); } else { STAGE_BLO(0, kt + 1); }           \
        VMCNTI(6);                                                                 \
        bar_acq();  phase_mfma<1, 0>(ar, br, acc);  bar_rel();                     \
        phase_read<1, 1, false, true>(smb, wave_m, wn, mrow, pcs, ar, br);         \
        if (nb) { STAGE_BHI(1, kt + 1); } else { STAGE_BHI(0, kt + 1); }           \
        bar_acq();  phase_mfma<1, 1>(ar, br, acc);  bar_rel();                     \
        phase_read<0, 1, true, false>(smb, wave_m, wn, mrow, pcs, ar, br);         \
        VMCNTI(2);                                                                 \
        bar_acq();  phase_mfma<0, 1>(ar, br, acc);  bar_rel();                     \
    }                                                                              \
    VMCNT0;                                                                        \
    __builtin_amdgcn_s_barrier();                                                  \
    MEMFENCE;                                                                      \
    {                                                                              \
        const __bf16* smb = &sm[1][0];                                             \
        phase_read<0, 0, true, true >(smb, wave_m, wn, mrow, pcs, ar, br);         \
        LGKM0; __builtin_amdgcn_sched_barrier(0);  phase_mfma<0, 0>(ar, br, acc);  \
        phase_read<1, 0, true, false>(smb, wave_m, wn, mrow, pcs, ar, br);         \
        LGKM0; __builtin_amdgcn_sched_barrier(0);  phase_mfma<1, 0>(ar, br, acc);  \
        phase_read<1, 1, false, true>(smb, wave_m, wn, mrow, pcs, ar, br);         \
        LGKM0; __builtin_amdgcn_sched_barrier(0);  phase_mfma<1, 1>(ar, br, acc);  \
        phase_read<0, 1, true, false>(smb, wave_m, wn, mrow, pcs, ar, br);         \
        LGKM0; __builtin_amdgcn_sched_barrier(0);  phase_mfma<0, 1>(ar, br, acc);  \
    }

// ---------------- fused GEMM + LSTM cell (256x256, gate-strip B) ----------------
__global__ __launch_bounds__(512, 2) void gemm_lstm(const __bf16* __restrict__ A,
                                                    const __bf16* __restrict__ Bm,
                                                    const float* __restrict__ traj,
                                                    const float* __restrict__ wih_i,
                                                    const float* __restrict__ bsum,
                                                    float* __restrict__ c,
                                                    __bf16* __restrict__ h_out,
                                                    int t) {
    __shared__ __bf16 sm[2][32768];   // 128 KiB

    const int tid    = threadIdx.x;
    const int lane   = tid & 63;
    const int wave   = tid >> 6;
    const int wave_m = wave & 1;
    const int wn     = wave >> 1;
    const int bm     = blockIdx.x;    // rows [bm*256, +256)
    const int ub     = blockIdx.y;    // units [ub*64, +64)

    const int mrow = lane & 15;
    const int pcs  = (((lane >> 4) ^ (mrow & 7)) << 3);   // fixed 3-bit-XOR read slot

    // pre-swizzled global staging sources: chunk ca = tid + s*512; row r=ca>>3,
    // physical slot p=ca&7 -> logical slot l = p ^ (r&7).
    const __bf16* pa[4];
    const __bf16* pb[4];
    #pragma unroll
    for (int s = 0; s < 4; ++s) {
        const int ca = tid + s * 512;
        const int r  = ca >> 3;
        const int l  = (ca & 7) ^ (r & 7);
        pa[s] = A + (size_t)(bm * 256 + r) * HID + l * 8;
        const int g = r >> 6, ul = r & 63;
        pb[s] = Bm + (size_t)(g * HID + ub * 64 + ul) * HID + l * 8;
    }
    const int wb = wave * 512;        // wave-uniform LDS elem base

    GEMM256_BODY

    // ---- register-only cell update: lane owns unit u_glob; 8x4 cells ----
    const int u_glob = ub * 64 + wn * 16 + mrow;
    const int crow4  = (lane >> 4) * 4;
    float wv[4][4], bs4[4];
    #pragma unroll
    for (int gi = 0; gi < 4; ++gi) {
        float4 wp = *(const float4*)(wih_i + (size_t)(u_glob * 4 + gi) * 4);
        wv[gi][0] = wp.x; wv[gi][1] = wp.y; wv[gi][2] = wp.z; wv[gi][3] = wp.w;
        bs4[gi] = bsum[u_glob * 4 + gi];
    }
    #pragma unroll
    for (int i = 0; i < 8; ++i) {
        const int growb = bm * 256 + wave_m * 128 + (i >> 2) * 64 + (i & 3) * 16 + crow4;
        #pragma unroll
        for (int r = 0; r < 4; ++r) {
            const int grow = growb + r;
            const float4 x = *(const float4*)(traj + (size_t)grow * (HLEN * IND) + t * IND);
            float g[4];
            #pragma unroll
            for (int gi = 0; gi < 4; ++gi)
                g[gi] = acc[i][gi][r] + bs4[gi]
                      + wv[gi][0] * x.x + wv[gi][1] * x.y + wv[gi][2] * x.z + wv[gi][3] * x.w;
            float ig = sigmf(g[0]);
            float fg = sigmf(g[1]);
            float gg = tanh_fast(g[2]);
            float og = sigmf(g[3]);
            size_t ci = (size_t)grow * HID + u_glob;
            float cn = fg * c[ci] + ig * gg;
            c[ci] = cn;
            h_out[ci] = (__bf16)(og * tanh_fast(cn));
        }
    }
}

// ---------------- projection GEMM (256x256): hrel = h @ W_rel^T, bf16 out ----------------
__global__ __launch_bounds__(512, 2) void gemm_proj(const __bf16* __restrict__ A,
                                                    const __bf16* __restrict__ Bm,
                                                    __bf16* __restrict__ Cout) {
    __shared__ __bf16 sm[2][32768];

    const int tid    = threadIdx.x;
    const int lane   = tid & 63;
    const int wave   = tid >> 6;
    const int wave_m = wave & 1;
    const int wn     = wave >> 1;
    const int bm     = blockIdx.x;    // rows [bm*256, +256)
    const int bn     = blockIdx.y;    // cols [bn*256, +256)

    const int mrow = lane & 15;
    const int pcs  = (((lane >> 4) ^ (mrow & 7)) << 3);

    const __bf16* pa[4];
    const __bf16* pb[4];
    #pragma unroll
    for (int s = 0; s < 4; ++s) {
        const int ca = tid + s * 512;
        const int r  = ca >> 3;
        const int l  = (ca & 7) ^ (r & 7);
        pa[s] = A  + (size_t)(bm * 256 + r) * HID + l * 8;
        pb[s] = Bm + (size_t)(bn * 256 + r) * HID + l * 8;
    }
    const int wb = wave * 512;

    GEMM256_BODY

    const int crow4 = (lane >> 4) * 4;
    #pragma unroll
    for (int i = 0; i < 8; ++i) {
        const int growb = bm * 256 + wave_m * 128 + (i >> 2) * 64 + (i & 3) * 16 + crow4;
        #pragma unroll
        for (int j = 0; j < 4; ++j) {
            const int gcol = bn * 256 + j * 64 + wn * 16 + mrow;
            #pragma unroll
            for (int r = 0; r < 4; ++r)
                Cout[(size_t)(growb + r) * DD + gcol] = (__bf16)acc[i][j][r];
        }
    }
}

// ---------------- fused gate-mix + residual + LayerNorm ----------------
__global__ __launch_bounds__(256) void fuse_ln(const float* __restrict__ tokens,
                                               const __bf16* __restrict__ hrel,
                                               const float* __restrict__ habs_in,
                                               const float* __restrict__ W_abs,
                                               const float* __restrict__ alpha,
                                               const float* __restrict__ gamma,
                                               const float* __restrict__ beta,
                                               float* __restrict__ out) {
    const int row = blockIdx.x;
    const int b   = row >> 9;
    const float al = alpha[b];
    const float a0 = habs_in[(size_t)row * 2];
    const float a1 = habs_in[(size_t)row * 2 + 1];
    const int tid  = threadIdx.x;
    const int lane = tid & 63;
    const int wave = tid >> 6;

    __shared__ float red[4];

    float x[4];
    float s = 0.0f;
    #pragma unroll
    for (int q = 0; q < 4; ++q) {
        int dcol = tid + q * 256;
        float habs = a0 * W_abs[dcol * 2] + a1 * W_abs[dcol * 2 + 1];
        float v = tokens[(size_t)row * DD + dcol]
                + al * (float)hrel[(size_t)row * DD + dcol]
                + (1.0f - al) * habs;
        x[q] = v;
        s += v;
    }
    #pragma unroll
    for (int off = 32; off > 0; off >>= 1) s += __shfl_down(s, off);
    if (lane == 0) red[wave] = s;
    __syncthreads();
    float mu = (red[0] + red[1] + red[2] + red[3]) * (1.0f / DD);

    float vs = 0.0f;
    #pragma unroll
    for (int q = 0; q < 4; ++q) {
        float d = x[q] - mu;
        vs += d * d;
    }
    #pragma unroll
    for (int off = 32; off > 0; off >>= 1) vs += __shfl_down(vs, off);
    __syncthreads();
    if (lane == 0) red[wave] = vs;
    __syncthreads();
    float var = (red[0] + red[1] + red[2] + red[3]) * (1.0f / DD);
    float rstd = rsqrtf(var + EPS);

    #pragma unroll
    for (int q = 0; q < 4; ++q) {
        int dcol = tid + q * 256;
        out[(size_t)row * DD + dcol] = (x[q] - mu) * rstd * gamma[dcol] + beta[dcol];
    }
}

// ---------------- host launch ----------------
extern "C" void kernel_launch(void* const* d_in, const int* in_sizes, int n_in,
                              void* d_out, int out_size, void* d_ws, size_t ws_size,
                              hipStream_t stream) {
    const float* tokens   = (const float*)d_in[0];
    const float* traj     = (const float*)d_in[1];
    const float* habs     = (const float*)d_in[2];
    const float* espeed   = (const float*)d_in[3];
    const float* gconf    = (const float*)d_in[4];
    const float* W_ih     = (const float*)d_in[5];
    const float* W_hh     = (const float*)d_in[6];
    const float* b_ih     = (const float*)d_in[7];
    const float* b_hh     = (const float*)d_in[8];
    const float* W_rel    = (const float*)d_in[9];
    const float* W_abs    = (const float*)d_in[10];
    const float* W_g1     = (const float*)d_in[11];
    const float* b_g1     = (const float*)d_in[12];
    const float* W_g2     = (const float*)d_in[13];
    const float* b_g2     = (const float*)d_in[14];
    const float* gamma    = (const float*)d_in[15];
    const float* beta     = (const float*)d_in[16];
    float* out = (float*)d_out;

    char* ws = (char*)d_ws;
    size_t off = 0;
    __bf16* whh_b  = (__bf16*)(ws + off); off += (size_t)G4 * HID * 2;     // 2 MB
    __bf16* wrel_b = (__bf16*)(ws + off); off += (size_t)DD * HID * 2;     // 1 MB
    float*  wih_i  = (float*)(ws + off);  off += (size_t)G4 * 4 * 4;       // 32 KB
    float*  bsum   = (float*)(ws + off);  off += (size_t)G4 * 4;           // 8 KB
    __bf16* h0     = (__bf16*)(ws + off); off += (size_t)BN * HID * 2;     // 16 MB
    __bf16* h1     = (__bf16*)(ws + off); off += (size_t)BN * HID * 2;     // 16 MB
    float*  c      = (float*)(ws + off);  off += (size_t)BN * HID * 4;     // 32 MB
    __bf16* hrel   = (__bf16*)(ws + off); off += (size_t)BN * DD * 2;      // 32 MB
    float*  alpha  = (float*)(ws + off);  off += 256;

    convert_w<<<(G4 * HID + 255) / 256, 256, 0, stream>>>(W_hh, W_rel, W_ih, b_ih, b_hh,
                                                          whh_b, wrel_b, wih_i, bsum);
    alpha_kernel<<<1, 64, 0, stream>>>(espeed, gconf, W_g1, b_g1, W_g2, b_g2, alpha);
    lstm_cell0<<<(BN * HID) / 256, 256, 0, stream>>>(traj, wih_i, bsum, c, h0);

    __bf16* hbuf[2] = {h0, h1};
    for (int t = 1; t < HLEN; ++t) {
        const __bf16* hin = hbuf[(t + 1) & 1];
        __bf16* hout = hbuf[t & 1];
        gemm_lstm<<<dim3(BN / 256, HID / 64), 512, 0, stream>>>(hin, whh_b, traj, wih_i, bsum,
                                                                c, hout, t);
    }
    // final h after t=14 is in hbuf[14&1] = h0
    gemm_proj<<<dim3(BN / 256, DD / 256), 512, 0, stream>>>(h0, wrel_b, hrel);
    fuse_ln<<<BN, 256, 0, stream>>>(tokens, hrel, habs, W_abs, alpha, gamma, beta, out);
}